// Round 7
// baseline (1464.865 us; speedup 1.0000x reference)
//
#include <hip/hip_runtime.h>
#include <math.h>

namespace {
constexpr int kS = 2048;
constexpr int kD = 64;
constexpr int kBH = 32;              // B*H = 2*16
constexpr int kTopK = 32;
constexpr int kBins = 4096;          // 12-bit radix on sortable float bits
constexpr int kMaxCand = 256;        // cap for values sharing the pivot bin
constexpr int kKeepCap = 64;         // cap for kept (idx, weight) list
constexpr size_t kCtxElems  = (size_t)kBH * kS * kD;   // 4,194,304
constexpr size_t kAttnElems = (size_t)kBH * kS * kS;   // 134,217,728
}

__device__ __forceinline__ unsigned sortable_bits(float x) {
  unsigned u = __float_as_uint(x);
  return u ^ ((u & 0x80000000u) ? 0xFFFFFFFFu : 0x80000000u);
}

// ---------------------------------------------------------------------------
// Kernel 1: scores = Q K^T / 8, fp32.
// BIT-EXACTNESS INVARIANT (round-4 pass): every score element is a single
// fp32 accumulator chain `acc += a*b` with k STRICTLY ASCENDING, scaled by
// 0.125f at the end. Shape is free; the per-element chain is frozen.
// R7 structure: block owns a 64-row q-tile (staged to LDS once) and loops
// over all 16 k-tiles (128 cols each) with REGISTER PREFETCH of tile t+1
// during compute of tile t — staging hidden under FMA instead of serialized.
// LDS 52.3 KB -> 3 blocks/CU (12 waves).
// ---------------------------------------------------------------------------
__global__ __launch_bounds__(256) void qk_scores(const float* __restrict__ q,
                                                 const float* __restrict__ k,
                                                 float* __restrict__ scores) {
  __shared__ float QsT[64][72];    // [d][q-row]  18.4 KB, staged once
  __shared__ float KsT[64][132];   // [d][col]    33.8 KB, per k-tile
  const int bh  = blockIdx.y;
  const int q0  = blockIdx.x * 64;
  const int tid = threadIdx.x;
  const float* qg = q + ((size_t)bh * kS + q0) * kD;   // 64 rows x 64
  const float* kg = k + (size_t)bh * kS * kD;

  // Stage q-tile transposed [d][row]; 4096 floats, 4 float4/thread.
#pragma unroll
  for (int p = 0; p < 4; ++p) {
    int flat = p * 1024 + tid * 4;
    int r = flat >> 6, c = flat & 63;
    float4 v4 = *(const float4*)(qg + flat);
    QsT[c + 0][r] = v4.x;
    QsT[c + 1][r] = v4.y;
    QsT[c + 2][r] = v4.z;
    QsT[c + 3][r] = v4.w;
  }

  // Prefetch k-tile 0 into registers (8192 floats, 8 float4/thread).
  float4 pf[8];
#pragma unroll
  for (int p = 0; p < 8; ++p)
    pf[p] = *(const float4*)(kg + p * 1024 + tid * 4);

  const int ty8 = (tid >> 5) * 8;   // q rows ty8..ty8+7
  const int tx4 = (tid & 31) * 4;   // k cols (within tile) tx4..tx4+3

  for (int t = 0; t < 16; ++t) {
    __syncthreads();   // previous compute done reading KsT
    // Commit prefetched tile t to LDS (transposed [d][col]).
#pragma unroll
    for (int p = 0; p < 8; ++p) {
      int flat = p * 1024 + tid * 4;
      int r = flat >> 6, c = flat & 63;   // r = col-row within tile (0..127)
      KsT[c + 0][r] = pf[p].x;
      KsT[c + 1][r] = pf[p].y;
      KsT[c + 2][r] = pf[p].z;
      KsT[c + 3][r] = pf[p].w;
    }
    __syncthreads();
    // Issue prefetch for tile t+1 (consumed next iteration — hidden by FMAs).
    if (t < 15) {
      const float* kt = kg + (size_t)(t + 1) * 128 * kD;
#pragma unroll
      for (int p = 0; p < 8; ++p)
        pf[p] = *(const float4*)(kt + p * 1024 + tid * 4);
    }

    // Compute 64x128 score tile; 8x4 microtile per thread.
    float acc[8][4] = {};
#pragma unroll
    for (int d4 = 0; d4 < 64; d4 += 4) {
      float a[4][8], b[4][4];
#pragma unroll
      for (int u = 0; u < 4; ++u) {
        *(float4*)(&a[u][0]) = *(const float4*)(&QsT[d4 + u][ty8]);
        *(float4*)(&a[u][4]) = *(const float4*)(&QsT[d4 + u][ty8 + 4]);
        *(float4*)(&b[u][0]) = *(const float4*)(&KsT[d4 + u][tx4]);
      }
      // Per-element d order: d4 outer, u inner ascending -> frozen chain.
#pragma unroll
      for (int i = 0; i < 8; ++i)
#pragma unroll
        for (int u = 0; u < 4; ++u)
#pragma unroll
          for (int j = 0; j < 4; ++j)
            acc[i][j] += a[u][i] * b[u][j];
    }

    const int c0 = t * 128 + tx4;
#pragma unroll
    for (int i = 0; i < 8; ++i) {
      float4 o = make_float4(acc[i][0] * 0.125f, acc[i][1] * 0.125f,
                             acc[i][2] * 0.125f, acc[i][3] * 0.125f);
      *(float4*)(scores + ((size_t)bh * kS + q0 + ty8 + i) * kS + c0) = o;
    }
  }
}

// ---------------------------------------------------------------------------
// Kernel 2 (unchanged from round 5/6): one 256-thread block per query row.
// Selection semantics identical to the round-4 pass:
//   t32 = 32nd-largest fp32 VALUE (duplicates counted), keep = score >= t32.
// ---------------------------------------------------------------------------
__global__ __launch_bounds__(256) void topk_softmax(const float* __restrict__ v,
                                                    float* __restrict__ ctx,
                                                    float* __restrict__ attn,
                                                    float* __restrict__ mask) {
  const int row  = blockIdx.x;     // bh*2048 + qi
  const int bh   = row >> 11;
  const int tid  = threadIdx.x;
  const int lane = tid & 63;
  const int wid  = tid >> 6;

  __shared__ unsigned s_hist[kBins];       // 16 KB
  __shared__ float    s_cand[kMaxCand];    // 1 KB
  __shared__ int      s_kidx[kKeepCap];
  __shared__ float    s_kw[kKeepCap];
  __shared__ float    s_wmax[4], s_wsum[4];
  __shared__ unsigned s_T[4];
  __shared__ unsigned s_nc, s_nk;
  __shared__ int      s_bstar, s_gabove;
  __shared__ float    s_t32;

  // P0: load scores (registers) + zero hist.
  const float* srow = attn + (size_t)row * kS;   // scores from kernel 1
  float4 l0 = *(const float4*)(srow + tid * 4);
  float4 l1 = *(const float4*)(srow + 1024 + tid * 4);
  float locv[8] = {l0.x, l0.y, l0.z, l0.w, l1.x, l1.y, l1.z, l1.w};
  int   loce[8];
#pragma unroll
  for (int j = 0; j < 8; ++j)
    loce[j] = (j < 4) ? (tid * 4 + j) : (1024 + tid * 4 + (j - 4));
#pragma unroll
  for (int i = 0; i < 4; ++i)
    *(uint4*)(&s_hist[tid * 16 + i * 4]) = make_uint4(0u, 0u, 0u, 0u);
  if (tid == 0) { s_nc = 0u; s_nk = 0u; }
  __syncthreads();

  // P1: histogram + per-wave max.
  unsigned bins[8];
  float pmax = locv[0];
#pragma unroll
  for (int j = 0; j < 8; ++j) {
    bins[j] = sortable_bits(locv[j]) >> 20;
    atomicAdd(&s_hist[bins[j]], 1u);
    pmax = fmaxf(pmax, locv[j]);
  }
#pragma unroll
  for (int off = 32; off >= 1; off >>= 1)
    pmax = fmaxf(pmax, __shfl_xor(pmax, off));
  if (lane == 0) s_wmax[wid] = pmax;
  __syncthreads();

  // P2: chunk sums (16 bins/thread) + in-wave suffix scan via shfl.
  unsigned lsum = 0;
#pragma unroll
  for (int j = 0; j < 16; ++j) lsum += s_hist[tid * 16 + j];
  unsigned sfx = lsum;
#pragma unroll
  for (int off = 1; off < 64; off <<= 1) {
    unsigned z = __shfl_down(sfx, off);
    if (lane + off < 64) sfx += z;
  }
  if (lane == 0) s_T[wid] = sfx;   // this wave's 64-chunk total
  __syncthreads();

  // P3: global suffix, locate pivot bin bstar and g_above.
  unsigned hi = 0;
#pragma unroll
  for (int w = 0; w < 4; ++w)
    if (w > wid) hi += s_T[w];
  unsigned gsfx  = sfx + hi;        // inclusive suffix (chunks >= mine)
  unsigned above = gsfx - lsum;     // exclusive
  if (gsfx >= (unsigned)kTopK && above < (unsigned)kTopK) {
    unsigned run = above;
    for (int j = 15; j >= 0; --j) {
      unsigned h = s_hist[tid * 16 + j];
      if (run < (unsigned)kTopK && run + h >= (unsigned)kTopK) {
        s_bstar  = tid * 16 + j;
        s_gabove = (int)run;        // elements in bins strictly above pivot
      }
      run += h;
    }
  }
  __syncthreads();
  const int   bstar  = s_bstar;
  const int   gabove = s_gabove;
  const float mx = fmaxf(fmaxf(s_wmax[0], s_wmax[1]),
                         fmaxf(s_wmax[2], s_wmax[3]));

  // P4: collect pivot-bin values.
#pragma unroll
  for (int j = 0; j < 8; ++j) {
    if ((int)bins[j] == bstar) {
      unsigned pos = atomicAdd(&s_nc, 1u);
      if (pos < (unsigned)kMaxCand) s_cand[pos] = locv[j];
    }
  }
  __syncthreads();
  const int m2 = (int)min(s_nc, (unsigned)kMaxCand);

  // P5: t32 = value with gabove+g < 32 <= gabove+g+e (equal values all share
  // the pivot bin, so e counted here is complete).
  for (int c = tid; c < m2; c += 256) {
    float x = s_cand[c];
    int g = 0, e = 0;
    for (int j2 = 0; j2 < m2; ++j2) {
      float y = s_cand[j2];
      g += (y > x);
      e += (y == x);
    }
    int G = gabove + g;
    if (G < kTopK && G + e >= kTopK) s_t32 = x;
  }
  __syncthreads();
  const float t32 = s_t32;

  // P6: weights, partial Z, kept-list for ctx.
  float w8[8];
  float psum = 0.0f;
#pragma unroll
  for (int j = 0; j < 8; ++j) {
    bool keep = (locv[j] >= t32);
    float wv = keep ? __expf(locv[j] - mx) : 0.0f;
    w8[j] = wv;
    psum += wv;
    if (keep) {
      unsigned p = atomicAdd(&s_nk, 1u);
      if (p < (unsigned)kKeepCap) { s_kidx[p] = loce[j]; s_kw[p] = wv; }
    }
  }
#pragma unroll
  for (int off = 32; off >= 1; off >>= 1)
    psum += __shfl_xor(psum, off);
  if (lane == 0) s_wsum[wid] = psum;
  __syncthreads();

  const float Z = s_wsum[0] + s_wsum[1] + s_wsum[2] + s_wsum[3];
  const float invZ = 1.0f / Z;

  // P7: write attn + mask straight from registers (coalesced float4).
  float* arow = attn + (size_t)row * kS;
  float* mrow = mask + (size_t)row * kS;
  float4 a0 = make_float4(w8[0] * invZ, w8[1] * invZ, w8[2] * invZ, w8[3] * invZ);
  float4 a1 = make_float4(w8[4] * invZ, w8[5] * invZ, w8[6] * invZ, w8[7] * invZ);
  float4 m0 = make_float4(locv[0] >= t32 ? 0.f : 1.f, locv[1] >= t32 ? 0.f : 1.f,
                          locv[2] >= t32 ? 0.f : 1.f, locv[3] >= t32 ? 0.f : 1.f);
  float4 m1 = make_float4(locv[4] >= t32 ? 0.f : 1.f, locv[5] >= t32 ? 0.f : 1.f,
                          locv[6] >= t32 ? 0.f : 1.f, locv[7] >= t32 ? 0.f : 1.f);
  *(float4*)(arow + tid * 4)        = a0;
  *(float4*)(arow + 1024 + tid * 4) = a1;
  *(float4*)(mrow + tid * 4)        = m0;
  *(float4*)(mrow + 1024 + tid * 4) = m1;

  // P8: context via wave 0 (lane = d), coalesced v reads, ~32 kept rows.
  if (tid < kD) {
    const int nk = (int)min(s_nk, (unsigned)kKeepCap);
    float acc = 0.0f;
    for (int c = 0; c < nk; ++c)
      acc += s_kw[c] * v[((size_t)bh * kS + s_kidx[c]) * kD + tid];
    ctx[(size_t)row * kD + tid] = acc * invZ;
  }
}

extern "C" void kernel_launch(void* const* d_in, const int* in_sizes, int n_in,
                              void* d_out, int out_size, void* d_ws, size_t ws_size,
                              hipStream_t stream) {
  const float* q = (const float*)d_in[0];
  const float* k = (const float*)d_in[1];
  const float* v = (const float*)d_in[2];
  float* out  = (float*)d_out;
  float* ctx  = out;
  float* attn = out + kCtxElems;
  float* mask = attn + kAttnElems;

  dim3 g1(kS / 64, kBH);
  qk_scores<<<g1, 256, 0, stream>>>(q, k, attn);
  topk_softmax<<<dim3(kBH * kS), 256, 0, stream>>>(v, ctx, attn, mask);
}